// Round 19
// baseline (59.517 us; speedup 1.0000x reference)
//
#include <hip/hip_runtime.h>
#include <hip/hip_bf16.h>
#include <hip/hip_fp8.h>
#include <stdint.h>

// Problem constants (from reference)
#define BATCH 4096
#define D_X   1024
#define D_Y   512

constexpr float SIGMA_INV = 0.1f;    // 1/10.0
constexpr float EPS_THR   = 46.0f;

// ---- fast path: fp8 e4m3, 128x128 tiles, BK=64, 2x16KB bufs, 4 blk/CU ----
constexpr int BMF   = 128;
constexpr int NTF   = BATCH / BMF;           // 32 tile-rows
constexpr int NBLKF = NTF * (NTF + 1) / 2;   // 528 (<= 1024 slots: 1 round)
constexpr int XRB   = D_X;                   // 1024 B per fp8 x row
constexpr int YRB   = D_Y;                   // 512 B per fp8 y row

// ---- fallback tiling (128^2 bf16, round-2 structure) ----
constexpr int BM = 128;
constexpr int NT = BATCH / BM;
constexpr int NBLK = NT * (NT + 1) / 2;

typedef __bf16 bf16x8 __attribute__((ext_vector_type(8)));
typedef float  f32x4  __attribute__((ext_vector_type(4)));
typedef unsigned short u16x8 __attribute__((ext_vector_type(8)));
typedef unsigned long long u64;
typedef u64 u64x2 __attribute__((ext_vector_type(2)));

__device__ __forceinline__ unsigned short f32_to_bf16_bits(float f) {
    unsigned int u = __builtin_bit_cast(unsigned int, f);
    unsigned int r = (u + 0x7FFFu + ((u >> 16) & 1u)) >> 16;  // RNE
    return (unsigned short)r;
}

// Per-8 k-u64 permutation: within each 8-u64 group (K=64), stored 16B chunk
// c holds logical k-u64s {c, c+4} = the two K=32 fragments of kgrp c ->
// one ds_read_b128 per (row, kgrp) per BK=64 step.
__device__ __forceinline__ int perm8(int ug) {
    return (ug & 3) * 2 + ((ug >> 2) & 1);
}

// ===========================================================================
// FAST PATH kernel 1: f32 -> fp8 e4m3 (per-8 permuted k-order) + norms of
// the QUANTIZED values (d2 = ||q_i - q_j||^2 exact for quantized vectors).
// ===========================================================================
__global__ void __launch_bounds__(192)
convert_fp8(const float* __restrict__ x, const float* __restrict__ y,
            u64* __restrict__ xq, u64* __restrict__ yq,
            float* __restrict__ sqx, float* __restrict__ sqy) {
    __shared__ float part[2];
    const int row = blockIdx.x;
    const int t   = threadIdx.x;
    const int lane = t & 63;
    const int wid  = t >> 6;

    float nrm = 0.f;
    if (t < 128) {
        const float4* p = (const float4*)(x + (size_t)row * D_X + t * 8);
        float4 f0 = p[0], f1 = p[1];
        float e[8] = {f0.x, f0.y, f0.z, f0.w, f1.x, f1.y, f1.z, f1.w};
        u64 w = 0;
#pragma unroll
        for (int i = 0; i < 8; ++i) {
            __hip_fp8_e4m3 q(e[i]);                  // RNE + saturate (OCP)
            float b = (float)q;
            nrm = fmaf(b, b, nrm);
            w |= (u64)q.__x << (8 * i);
        }
        xq[(size_t)row * 128 + (t & ~7) + perm8(t & 7)] = w;
    } else {
        int o = t - 128;                             // 0..63
        const float4* p = (const float4*)(y + (size_t)row * D_Y + o * 8);
        float4 f0 = p[0], f1 = p[1];
        float e[8] = {f0.x, f0.y, f0.z, f0.w, f1.x, f1.y, f1.z, f1.w};
        u64 w = 0;
#pragma unroll
        for (int i = 0; i < 8; ++i) {
            __hip_fp8_e4m3 q(e[i]);
            float b = (float)q;
            nrm = fmaf(b, b, nrm);
            w |= (u64)q.__x << (8 * i);
        }
        yq[(size_t)row * 64 + (o & ~7) + perm8(o & 7)] = w;
    }
#pragma unroll
    for (int off = 32; off > 0; off >>= 1)
        nrm += __shfl_down(nrm, off, 64);
    if (lane == 0) {
        if (wid < 2) part[wid] = nrm;
        else         sqy[row] = nrm;
    }
    __syncthreads();
    if (t == 0) sqx[row] = part[0] + part[1];
}

// ===========================================================================
// FAST PATH kernel 2: 128^2 fp8 tiles, BK=64 -> 24 steps, 2 x 16 KB buffers
// (~34 KB LDS -> 4 blocks/CU; all 528 blocks co-resident, no tail round).
// LDS tile: [128 lines][8 x 16B slots]; line l packs rows {2l, 2l+1} of the
// combined 256-row A|B stack (row parity -> slots 0-3 / 4-7). Fragment read
// T[line*8 + (row&1)*4 + kgrp] covers all 8 slots of 8 lines evenly ->
// bank-conflict floor WITHOUT any XOR swizzle. Champion (R14) sync skeleton:
// counted vmcnt(4), mid-barrier read-all-then-issue, pointer-arith offsets
// (global_load_lds offset arg stays 0 - R12: imm applies to BOTH addresses).
// ===========================================================================

#define ISSUE(DST, BASE, OFF)                                              \
    {                                                                      \
        _Pragma("unroll")                                                  \
        for (int it = 0; it < 4; ++it)                                     \
            __builtin_amdgcn_global_load_lds(                              \
                (const uint32_t __attribute__((address_space(1)))*)(BASE[it] + (OFF)), \
                (uint32_t __attribute__((address_space(3)))*)((DST) + it * 256 + wid * 64), \
                16, 0, 0);                                                 \
    }

#define FRAGS_READ(BUF)                                                    \
        u64x2 fa[4], fb[4];                                                \
        _Pragma("unroll")                                                  \
        for (int m = 0; m < 4; ++m) {                                      \
            int row = wr * 64 + m * 16 + lrow;                             \
            fa[m] = __builtin_bit_cast(u64x2,                              \
                (BUF)[(row >> 1) * 8 + (row & 1) * 4 + kgrp]);             \
        }                                                                  \
        _Pragma("unroll")                                                  \
        for (int n = 0; n < 4; ++n) {                                      \
            int row = 128 + wc * 64 + n * 16 + lrow;                       \
            fb[n] = __builtin_bit_cast(u64x2,                              \
                (BUF)[(row >> 1) * 8 + (row & 1) * 4 + kgrp]);             \
        }

#define FRAGS_MFMA(ACC)                                                    \
        __builtin_amdgcn_s_setprio(1);                                     \
        _Pragma("unroll")                                                  \
        for (int h = 0; h < 2; ++h)                                        \
            _Pragma("unroll")                                              \
            for (int m = 0; m < 4; ++m)                                    \
                _Pragma("unroll")                                          \
                for (int n = 0; n < 4; ++n)                                \
                    ACC[m][n] = __builtin_amdgcn_mfma_f32_16x16x32_fp8_fp8(\
                        (long)fa[m][h], (long)fb[n][h], ACC[m][n], 0,0,0); \
        __builtin_amdgcn_s_setprio(0);

#define GSTEP(BUF, ACC, W, IBASE, IOFF)                                    \
    {                                                                      \
        asm volatile("s_waitcnt vmcnt(" #W ")" ::: "memory");              \
        __builtin_amdgcn_s_barrier();                                      \
        FRAGS_READ(BUF)                                                    \
        asm volatile("s_waitcnt lgkmcnt(0)" ::: "memory");                 \
        __builtin_amdgcn_s_barrier();                                      \
        ISSUE(BUF, IBASE, IOFF)                                            \
        FRAGS_MFMA(ACC)                                                    \
    }
#define GSTEP_NOISSUE(BUF, ACC, W)                                         \
    {                                                                      \
        asm volatile("s_waitcnt vmcnt(" #W ")" ::: "memory");              \
        __builtin_amdgcn_s_barrier();                                      \
        FRAGS_READ(BUF)                                                    \
        FRAGS_MFMA(ACC)                                                    \
    }

__global__ void __launch_bounds__(256, 4)
gram_fp8(const u16x8* __restrict__ xq, const u16x8* __restrict__ yq,
         const float* __restrict__ sqx, const float* __restrict__ sqy,
         float* __restrict__ out) {
    __shared__ u16x8 T0[1024], T1[1024];   // 2 x 16 KB combined A|B tiles
    __shared__ float snxA[BMF], snxB[BMF], snyA[BMF], snyB[BMF];
    __shared__ float wsum[4];

    const int tid  = threadIdx.x;
    const int lane = tid & 63;
    const int wid  = tid >> 6;
    const int wr   = wid >> 1;
    const int wc   = wid & 1;
    const int lrow = lane & 15;
    const int kgrp = lane >> 4;

    // XCD swizzle (bijective: NBLKF % 8 == 0).
    int sb = (blockIdx.x & 7) * (NBLKF / 8) + (blockIdx.x >> 3);

    // triangular tile mapping
    int t0 = sb, bi = 0;
    while (t0 >= NTF - bi) { t0 -= NTF - bi; ++bi; }
    const int bj = bi + t0;
    const int iA = bi * BMF;
    const int iB = bj * BMF;
    const bool diag = (bi == bj);

    if (tid < BMF) {
        snxA[tid] = sqx[iA + tid];
        snyA[tid] = sqy[iA + tid];
    } else {
        int u = tid - BMF;
        snxB[u] = sqx[iB + u];
        snyB[u] = sqy[iB + u];
    }

    // Per-lane staging bases. LDS slot ul = it*256 + wid*64 + lane ->
    // line = ul>>3, slot = ul&7 -> row = 2*line + (slot>>2), chunk = slot&3.
    // Source byte = grow*rowbytes + chunk*16 (+ step*64 at issue).
    const char* gx[4];
    const char* gy[4];
#pragma unroll
    for (int it = 0; it < 4; ++it) {
        int ul   = it * 256 + wid * 64 + lane;
        int row  = 2 * (ul >> 3) + ((ul >> 2) & 1);
        int cg   = ul & 3;
        int grow = (row < 128 ? iA + row : iB + row - 128);
        gx[it] = (const char*)xq + (size_t)grow * XRB + cg * 16;
        gy[it] = (const char*)yq + (size_t)grow * YRB + cg * 16;
    }

    f32x4 accX[4][4] = {};
    f32x4 accY[4][4] = {};

    // prologue: pre-issue steps 0,1 (8 loads in flight; no drain)
    ISSUE(T0, gx, 0)
    ISSUE(T1, gx, 64)

    // X phase: steps 0..15 (K=1024); step s stages bytes s*64.
    GSTEP(T0, accX, 4, gx, 128)   // s0,  issues s2
    GSTEP(T1, accX, 4, gx, 192)   // s1,  issues s3
    GSTEP(T0, accX, 4, gx, 256)   // s2
    GSTEP(T1, accX, 4, gx, 320)   // s3
    GSTEP(T0, accX, 4, gx, 384)   // s4
    GSTEP(T1, accX, 4, gx, 448)   // s5
    GSTEP(T0, accX, 4, gx, 512)   // s6
    GSTEP(T1, accX, 4, gx, 576)   // s7
    GSTEP(T0, accX, 4, gx, 640)   // s8
    GSTEP(T1, accX, 4, gx, 704)   // s9
    GSTEP(T0, accX, 4, gx, 768)   // s10
    GSTEP(T1, accX, 4, gx, 832)   // s11
    GSTEP(T0, accX, 4, gx, 896)   // s12, issues s14
    GSTEP(T1, accX, 4, gx, 960)   // s13, issues s15
    GSTEP(T0, accX, 4, gy, 0)     // s14, issues s16 (first Y step)
    GSTEP(T1, accX, 4, gy, 64)    // s15, issues s17
    // Y phase: steps 16..23 (K=512)
    GSTEP(T0, accY, 4, gy, 128)   // s16, issues s18
    GSTEP(T1, accY, 4, gy, 192)   // s17
    GSTEP(T0, accY, 4, gy, 256)   // s18
    GSTEP(T1, accY, 4, gy, 320)   // s19
    GSTEP(T0, accY, 4, gy, 384)   // s20, issues s22
    GSTEP(T1, accY, 4, gy, 448)   // s21, issues s23
    GSTEP_NOISSUE(T0, accY, 4)    // s22 (batch 23 in flight)
    GSTEP_NOISSUE(T1, accY, 0)    // s23 (full drain)

    // Epilogue: C/D layout col=lane&15, row=(lane>>4)*4+reg (m89, dtype-indep)
    float local = 0.f;
#pragma unroll
    for (int m = 0; m < 4; ++m) {
#pragma unroll
        for (int n = 0; n < 4; ++n) {
            int col   = wc * 64 + n * 16 + lrow;
            float sxj = snxB[col];
            float syj = snyB[col];
#pragma unroll
            for (int r = 0; r < 4; ++r) {
                int rowi  = wr * 64 + m * 16 + kgrp * 4 + r;
                float d2x = snxA[rowi] + sxj - 2.f * accX[m][n][r];
                float dxv = sqrtf(fmaxf(d2x, 1e-12f));
                float d2y = snyA[rowi] + syj - 2.f * accY[m][n][r];
                float dyv = sqrtf(fmaxf(d2y, 1e-12f));
                int gi = iA + rowi, gj = iB + col;
                bool keep = (gi != gj) && (dxv <= EPS_THR);
                float contrib = __expf(-dxv * SIGMA_INV) * dyv;
                local += keep ? contrib : 0.f;
            }
        }
    }
    if (!diag) local *= 2.f;

#pragma unroll
    for (int off = 32; off > 0; off >>= 1)
        local += __shfl_down(local, off, 64);
    if (lane == 0) wsum[wid] = local;
    __syncthreads();
    if (tid == 0)
        atomicAdd(out, wsum[0] + wsum[1] + wsum[2] + wsum[3]);
}

// ===========================================================================
// FALLBACK PATH (bf16, round-2 structure) — used only if ws too small.
// ===========================================================================
__global__ void norms_kernel_fb(const float* __restrict__ x,
                                const float* __restrict__ y,
                                float* __restrict__ sqx,
                                float* __restrict__ sqy) {
    int row = blockIdx.x;
    int t   = threadIdx.x;
    const float4* xr = (const float4*)(x + (size_t)row * D_X);
    float sx = 0.f;
#pragma unroll
    for (int i = 0; i < D_X / 4 / 64; ++i) {
        float4 v = xr[t + i * 64];
        sx += v.x * v.x + v.y * v.y + v.z * v.z + v.w * v.w;
    }
    const float4* yr = (const float4*)(y + (size_t)row * D_Y);
    float sy = 0.f;
#pragma unroll
    for (int i = 0; i < D_Y / 4 / 64; ++i) {
        float4 v = yr[t + i * 64];
        sy += v.x * v.x + v.y * v.y + v.z * v.z + v.w * v.w;
    }
#pragma unroll
    for (int off = 32; off > 0; off >>= 1) {
        sx += __shfl_down(sx, off, 64);
        sy += __shfl_down(sy, off, 64);
    }
    if (t == 0) { sqx[row] = sx; sqy[row] = sy; }
}

__device__ __forceinline__ void stage_tile_fb(const float* __restrict__ src, int ld,
                                              int base_row, int k0,
                                              u16x8* __restrict__ dst, int tid) {
#pragma unroll
    for (int it = 0; it < 2; ++it) {
        int u   = tid + it * 256;
        int row = u >> 2;
        int q   = u & 3;
        const float4* p = (const float4*)(src + (size_t)(base_row + row) * ld + k0 + q * 16);
        float4 f0 = p[0], f1 = p[1], f2 = p[2], f3 = p[3];
        u16x8 lo, hi;
        lo[0] = f32_to_bf16_bits(f0.x); lo[1] = f32_to_bf16_bits(f0.y);
        lo[2] = f32_to_bf16_bits(f0.z); lo[3] = f32_to_bf16_bits(f0.w);
        lo[4] = f32_to_bf16_bits(f1.x); lo[5] = f32_to_bf16_bits(f1.y);
        lo[6] = f32_to_bf16_bits(f1.z); lo[7] = f32_to_bf16_bits(f1.w);
        hi[0] = f32_to_bf16_bits(f2.x); hi[1] = f32_to_bf16_bits(f2.y);
        hi[2] = f32_to_bf16_bits(f2.z); hi[3] = f32_to_bf16_bits(f2.w);
        hi[4] = f32_to_bf16_bits(f3.x); hi[5] = f32_to_bf16_bits(f3.y);
        hi[6] = f32_to_bf16_bits(f3.z); hi[7] = f32_to_bf16_bits(f3.w);
        int swz = row & 7;
        dst[row * 8 + ((2 * q) ^ swz)]     = lo;
        dst[row * 8 + ((2 * q + 1) ^ swz)] = hi;
    }
}

__device__ __forceinline__ void mfma16_fb(const bf16x8 a[4], const bf16x8 b[4],
                                          f32x4 acc[4][4]) {
#pragma unroll
    for (int m = 0; m < 4; ++m)
#pragma unroll
        for (int n = 0; n < 4; ++n)
            acc[m][n] = __builtin_amdgcn_mfma_f32_16x16x32_bf16(
                a[m], b[n], acc[m][n], 0, 0, 0);
}

__device__ __forceinline__ void load_frags_fb(const u16x8* As_, const u16x8* Bs_,
                                              int wr, int wc, int lrow, int kgrp,
                                              bf16x8 a[2][4], bf16x8 b[2][4]) {
#pragma unroll
    for (int ks = 0; ks < 2; ++ks) {
#pragma unroll
        for (int m = 0; m < 4; ++m) {
            int row  = wr * 64 + m * 16 + lrow;
            int slot = (ks * 4 + kgrp) ^ (row & 7);
            a[ks][m] = __builtin_bit_cast(bf16x8, As_[row * 8 + slot]);
        }
#pragma unroll
        for (int n = 0; n < 4; ++n) {
            int row  = wc * 64 + n * 16 + lrow;
            int slot = (ks * 4 + kgrp) ^ (row & 7);
            b[ks][n] = __builtin_bit_cast(bf16x8, Bs_[row * 8 + slot]);
        }
    }
}

__global__ void __launch_bounds__(256, 2)
graph_loss_fb(const float* __restrict__ x, const float* __restrict__ y,
              const float* __restrict__ sqx, const float* __restrict__ sqy,
              float* __restrict__ out) {
    __shared__ u16x8 As[BM * 8];
    __shared__ u16x8 Bs[BM * 8];
    __shared__ float snxA[BM], snxB[BM], snyA[BM], snyB[BM];
    __shared__ float wsum[4];

    const int tid  = threadIdx.x;
    const int lane = tid & 63;
    const int wid  = tid >> 6;
    const int wr   = wid >> 1;
    const int wc   = wid & 1;
    const int lrow = lane & 15;
    const int kgrp = lane >> 4;

    int t = blockIdx.x, bi = 0;
    while (t >= NT - bi) { t -= NT - bi; ++bi; }
    const int bj = bi + t;
    const int iA = bi * BM;
    const int iB = bj * BM;

    if (tid < BM) {
        snxA[tid] = sqx[iA + tid];
        snyA[tid] = sqy[iA + tid];
        snxB[tid] = sqx[iB + tid];
        snyB[tid] = sqy[iB + tid];
    }

    f32x4 accX[4][4] = {};
    f32x4 accY[4][4] = {};
    bf16x8 a[2][4], b[2][4];

    for (int kt = 0; kt < D_X / 64; ++kt) {
        __syncthreads();
        stage_tile_fb(x, D_X, iA, kt * 64, As, tid);
        stage_tile_fb(x, D_X, iB, kt * 64, Bs, tid);
        __syncthreads();
        load_frags_fb(As, Bs, wr, wc, lrow, kgrp, a, b);
#pragma unroll
        for (int ks = 0; ks < 2; ++ks) mfma16_fb(a[ks], b[ks], accX);
    }
    for (int kt = 0; kt < D_Y / 64; ++kt) {
        __syncthreads();
        stage_tile_fb(y, D_Y, iA, kt * 64, As, tid);
        stage_tile_fb(y, D_Y, iB, kt * 64, Bs, tid);
        __syncthreads();
        load_frags_fb(As, Bs, wr, wc, lrow, kgrp, a, b);
#pragma unroll
        for (int ks = 0; ks < 2; ++ks) mfma16_fb(a[ks], b[ks], accY);
    }

    float local = 0.f;
#pragma unroll
    for (int m = 0; m < 4; ++m) {
#pragma unroll
        for (int n = 0; n < 4; ++n) {
            int col   = wc * 64 + n * 16 + lrow;
            float sxj = snxB[col];
            float syj = snyB[col];
#pragma unroll
            for (int r = 0; r < 4; ++r) {
                int rowi  = wr * 64 + m * 16 + kgrp * 4 + r;
                float d2x = snxA[rowi] + sxj - 2.f * accX[m][n][r];
                float dxv = sqrtf(fmaxf(d2x, 1e-12f));
                float d2y = snyA[rowi] + syj - 2.f * accY[m][n][r];
                float dyv = sqrtf(fmaxf(d2y, 1e-12f));
                int gi = iA + rowi, gj = iB + col;
                bool keep = (gi != gj) && (dxv <= EPS_THR);
                float contrib = __expf(-dxv * SIGMA_INV) * dyv;
                local += keep ? contrib : 0.f;
            }
        }
    }
    if (bi != bj) local *= 2.f;

#pragma unroll
    for (int off = 32; off > 0; off >>= 1)
        local += __shfl_down(local, off, 64);
    if (lane == 0) wsum[wid] = local;
    __syncthreads();
    if (tid == 0)
        atomicAdd(out, wsum[0] + wsum[1] + wsum[2] + wsum[3]);
}

// ===========================================================================
extern "C" void kernel_launch(void* const* d_in, const int* in_sizes, int n_in,
                              void* d_out, int out_size, void* d_ws, size_t ws_size,
                              hipStream_t stream) {
    const float* x = (const float*)d_in[0];
    const float* y = (const float*)d_in[1];
    float* out = (float*)d_out;

    hipMemsetAsync(d_out, 0, sizeof(float) * (size_t)out_size, stream);

    const size_t xq_bytes = (size_t)BATCH * D_X;        // 4 MB fp8
    const size_t yq_bytes = (size_t)BATCH * D_Y;        // 2 MB fp8
    const size_t sq_bytes = 2 * (size_t)BATCH * sizeof(float);
    const size_t need = xq_bytes + yq_bytes + sq_bytes;

    if (ws_size >= need) {
        u64*   xq  = (u64*)d_ws;
        u64*   yq  = (u64*)((char*)d_ws + xq_bytes);
        float* sqx = (float*)((char*)d_ws + xq_bytes + yq_bytes);
        float* sqy = sqx + BATCH;
        convert_fp8<<<BATCH, 192, 0, stream>>>(x, y, xq, yq, sqx, sqy);
        gram_fp8<<<NBLKF, 256, 0, stream>>>((const u16x8*)xq, (const u16x8*)yq,
                                            sqx, sqy, out);
    } else {
        float* sqx = (float*)d_ws;
        float* sqy = sqx + BATCH;
        norms_kernel_fb<<<BATCH, 64, 0, stream>>>(x, y, sqx, sqy);
        graph_loss_fb<<<NBLK, 256, 0, stream>>>(x, y, sqx, sqy, out);
    }
}

// Round 20
// 57.203 us; speedup vs baseline: 1.0405x; 1.0405x over previous
//
#include <hip/hip_runtime.h>
#include <hip/hip_bf16.h>
#include <hip/hip_fp8.h>
#include <stdint.h>

// Problem constants (from reference)
#define BATCH 4096
#define D_X   1024
#define D_Y   512

constexpr float SIGMA_INV = 0.1f;    // 1/10.0
constexpr float EPS_THR   = 46.0f;

// ---- fast path: fp8 e4m3, 128x128 triangular tiles ----
constexpr int BMF   = 128;
constexpr int NTF   = BATCH / BMF;           // 32 tile-rows
constexpr int NBLKF = NTF * (NTF + 1) / 2;   // 528 (528 % 8 == 0)
constexpr int XS8   = D_X / 16;              // 64 16B slots per fp8 x row
constexpr int YS8   = D_Y / 16;              // 32 slots per fp8 y row

// ---- fallback tiling (128^2 bf16, round-2 structure) ----
constexpr int BM = 128;
constexpr int NT = BATCH / BM;
constexpr int NBLK = NT * (NT + 1) / 2;

typedef __bf16 bf16x8 __attribute__((ext_vector_type(8)));
typedef float  f32x4  __attribute__((ext_vector_type(4)));
typedef unsigned short u16x8 __attribute__((ext_vector_type(8)));
typedef unsigned long long u64;
typedef u64 u64x2 __attribute__((ext_vector_type(2)));

__device__ __forceinline__ unsigned short f32_to_bf16_bits(float f) {
    unsigned int u = __builtin_bit_cast(unsigned int, f);
    unsigned int r = (u + 0x7FFFu + ((u >> 16) & 1u)) >> 16;  // RNE
    return (unsigned short)r;
}

// k-unit permutation (R11): 16B chunk c = (ks>>1)*4 + kgrp holds ks-pair
// {2t,2t+1} of kgrp -> one conflict-free ds_read_b128 per (row, kspair).
__device__ __forceinline__ int perm16(int u8) {
    int ks = u8 >> 2, kg = u8 & 3;
    return (ks >> 1) * 8 + kg * 2 + (ks & 1);
}

// ===========================================================================
// FAST PATH kernel 1: f32 -> fp8 e4m3 (permuted k-order) + norms of the
// QUANTIZED values (so d2 = ||q_i - q_j||^2 is exact for quantized vectors).
// ===========================================================================
__global__ void __launch_bounds__(192)
convert_fp8(const float* __restrict__ x, const float* __restrict__ y,
            u64* __restrict__ xq, u64* __restrict__ yq,
            float* __restrict__ sqx, float* __restrict__ sqy) {
    __shared__ float part[2];
    const int row = blockIdx.x;
    const int t   = threadIdx.x;
    const int lane = t & 63;
    const int wid  = t >> 6;

    float nrm = 0.f;
    if (t < 128) {
        const float4* p = (const float4*)(x + (size_t)row * D_X + t * 8);
        float4 f0 = p[0], f1 = p[1];
        float e[8] = {f0.x, f0.y, f0.z, f0.w, f1.x, f1.y, f1.z, f1.w};
        u64 w = 0;
#pragma unroll
        for (int i = 0; i < 8; ++i) {
            __hip_fp8_e4m3 q(e[i]);                  // RNE + saturate (OCP)
            float b = (float)q;
            nrm = fmaf(b, b, nrm);
            w |= (u64)q.__x << (8 * i);
        }
        xq[(size_t)row * 128 + (t & ~15) + perm16(t & 15)] = w;
    } else {
        int o = t - 128;                             // 0..63
        const float4* p = (const float4*)(y + (size_t)row * D_Y + o * 8);
        float4 f0 = p[0], f1 = p[1];
        float e[8] = {f0.x, f0.y, f0.z, f0.w, f1.x, f1.y, f1.z, f1.w};
        u64 w = 0;
#pragma unroll
        for (int i = 0; i < 8; ++i) {
            __hip_fp8_e4m3 q(e[i]);
            float b = (float)q;
            nrm = fmaf(b, b, nrm);
            w |= (u64)q.__x << (8 * i);
        }
        yq[(size_t)row * 64 + (o & ~15) + perm16(o & 15)] = w;
    }
#pragma unroll
    for (int off = 32; off > 0; off >>= 1)
        nrm += __shfl_down(nrm, off, 64);
    if (lane == 0) {
        if (wid < 2) part[wid] = nrm;
        else         sqy[row] = nrm;
    }
    __syncthreads();
    if (t == 0) sqx[row] = part[0] + part[1];
}

// ===========================================================================
// FAST PATH kernel 2: 128^2 fp8 tiles. Combined A|B LDS tile [256 rows][8
// slots] = 32 KB/step, BK=128 -> 12 steps, 2 buffers (64 KB, 2 blocks/CU),
// depth-2 counted vmcnt(8). Per wave: 64x64 output, 64 MFMA/step.
// global_load_lds offset arg stays 0 (R12: the imm applies to BOTH global
// and LDS addresses); step offset is pointer arithmetic on the global side.
// ===========================================================================

__device__ __forceinline__ u64x2 ldsfrag2(const u16x8* T, int row, int c) {
    int slot = c ^ (row & 7);
    return __builtin_bit_cast(u64x2, T[row * 8 + slot]);
}

#define ISSUE(DST, BASE, OFF)                                              \
    {                                                                      \
        _Pragma("unroll")                                                  \
        for (int it = 0; it < 8; ++it)                                     \
            __builtin_amdgcn_global_load_lds(                              \
                (const uint32_t __attribute__((address_space(1)))*)(BASE[it] + (OFF)), \
                (uint32_t __attribute__((address_space(3)))*)((DST) + it * 256 + wid * 64), \
                16, 0, 0);                                                 \
    }

#define FRAGS_READ(BUF)                                                    \
        u64x2 fa[2][4], fb[2][4];   /* [kspair][frag] */                   \
        _Pragma("unroll")                                                  \
        for (int t2 = 0; t2 < 2; ++t2) {                                   \
            _Pragma("unroll")                                              \
            for (int m = 0; m < 4; ++m)                                    \
                fa[t2][m] = ldsfrag2(BUF, wr * 64 + m * 16 + lrow,         \
                                     t2 * 4 + kgrp);                       \
            _Pragma("unroll")                                              \
            for (int n = 0; n < 4; ++n)                                    \
                fb[t2][n] = ldsfrag2(BUF, 128 + wc * 64 + n * 16 + lrow,   \
                                     t2 * 4 + kgrp);                       \
        }

#define FRAGS_MFMA(ACC)                                                    \
        __builtin_amdgcn_s_setprio(1);                                     \
        _Pragma("unroll")                                                  \
        for (int t2 = 0; t2 < 2; ++t2)                                     \
            _Pragma("unroll")                                              \
            for (int h = 0; h < 2; ++h)                                    \
                _Pragma("unroll")                                          \
                for (int m = 0; m < 4; ++m)                                \
                    _Pragma("unroll")                                      \
                    for (int n = 0; n < 4; ++n)                            \
                        ACC[m][n] =                                        \
                            __builtin_amdgcn_mfma_f32_16x16x32_fp8_fp8(    \
                                (long)fa[t2][m][h], (long)fb[t2][n][h],    \
                                ACC[m][n], 0, 0, 0);                       \
        __builtin_amdgcn_s_setprio(0);

#define GSTEP(BUF, ACC, W, IBASE, IOFF)                                    \
    {                                                                      \
        asm volatile("s_waitcnt vmcnt(" #W ")" ::: "memory");              \
        __builtin_amdgcn_s_barrier();                                      \
        FRAGS_READ(BUF)                                                    \
        asm volatile("s_waitcnt lgkmcnt(0)" ::: "memory");                 \
        __builtin_amdgcn_s_barrier();                                      \
        ISSUE(BUF, IBASE, IOFF)                                            \
        FRAGS_MFMA(ACC)                                                    \
    }
#define GSTEP_NOISSUE(BUF, ACC, W)                                         \
    {                                                                      \
        asm volatile("s_waitcnt vmcnt(" #W ")" ::: "memory");              \
        __builtin_amdgcn_s_barrier();                                      \
        FRAGS_READ(BUF)                                                    \
        FRAGS_MFMA(ACC)                                                    \
    }

__global__ void __launch_bounds__(256, 2)
gram_fp8(const u16x8* __restrict__ xq, const u16x8* __restrict__ yq,
         const float* __restrict__ sqx, const float* __restrict__ sqy,
         float* __restrict__ out) {
    __shared__ u16x8 T0[2048], T1[2048];   // 2 x 32 KB combined A|B tiles
    __shared__ float snxA[BMF], snxB[BMF], snyA[BMF], snyB[BMF];
    __shared__ float wsum[4];

    const int tid  = threadIdx.x;
    const int lane = tid & 63;
    const int wid  = tid >> 6;
    const int wr   = wid >> 1;
    const int wc   = wid & 1;
    const int lrow = lane & 15;
    const int kgrp = lane >> 4;

    // XCD swizzle (bijective: NBLKF % 8 == 0).
    int sb = (blockIdx.x & 7) * (NBLKF / 8) + (blockIdx.x >> 3);

    // triangular tile mapping
    int t0 = sb, bi = 0;
    while (t0 >= NTF - bi) { t0 -= NTF - bi; ++bi; }
    const int bj = bi + t0;
    const int iA = bi * BMF;
    const int iB = bj * BMF;
    const bool diag = (bi == bj);

    if (tid < BMF) {
        snxA[tid] = sqx[iA + tid];
        snyA[tid] = sqy[iA + tid];
    } else {
        int u = tid - BMF;
        snxB[u] = sqx[iB + u];
        snyB[u] = sqy[iB + u];
    }

    // Per-lane staging base pointers: lane ul = it*256 + wid*64 + lane maps
    // to (row 0..255, stored-slot st); swizzle folded into the base.
    // X bases first; the same 8 registers are re-pointed at Y before step 6.
    const char* g[8];
#pragma unroll
    for (int it = 0; it < 8; ++it) {
        int ul   = it * 256 + wid * 64 + lane;
        int row  = ul >> 3;
        int st   = ul & 7;
        int lg   = st ^ (row & 7);
        int grow = (row < 128 ? iA + row : iB + row - 128);
        g[it] = (const char*)xq + (size_t)grow * (XS8 * 16) + lg * 16;
    }

    f32x4 accX[4][4] = {};
    f32x4 accY[4][4] = {};

    // prologue: pre-issue steps 0,1 (16 loads in flight; no drain)
    ISSUE(T0, g, 0)
    ISSUE(T1, g, 128)

    // X phase: steps 0..5 stage from xq (offsets s*128)
    GSTEP(T0, accX, 8, g, 256)   // s=0, issues s=2
    GSTEP(T1, accX, 8, g, 384)   // s=1, issues s=3
    GSTEP(T0, accX, 8, g, 512)   // s=2, issues s=4
    GSTEP(T1, accX, 8, g, 640)   // s=3, issues s=5
    GSTEP(T0, accX, 8, g, 768)   // s=4, issues s=6
    GSTEP(T1, accX, 8, g, 896)   // s=5, issues s=7

    // switch bases to yq (same registers; per-thread, no sync needed)
#pragma unroll
    for (int it = 0; it < 8; ++it) {
        int ul   = it * 256 + wid * 64 + lane;
        int row  = ul >> 3;
        int st   = ul & 7;
        int lg   = st ^ (row & 7);
        int grow = (row < 128 ? iA + row : iB + row - 128);
        g[it] = (const char*)yq + (size_t)grow * (YS8 * 16) + lg * 16;
    }

    GSTEP(T0, accX, 8, g, 0)     // s=6, issues s=8  (first Y step)
    GSTEP(T1, accX, 8, g, 128)   // s=7, issues s=9
    GSTEP(T0, accY, 8, g, 256)   // s=8, issues s=10
    GSTEP(T1, accY, 8, g, 384)   // s=9, issues s=11
    GSTEP_NOISSUE(T0, accY, 8)   // s=10 (batch 11 in flight)
    GSTEP_NOISSUE(T1, accY, 0)   // s=11 (full drain)

    // Epilogue: C/D layout col=lane&15, row=(lane>>4)*4+reg (m89, dtype-indep)
    float local = 0.f;
#pragma unroll
    for (int m = 0; m < 4; ++m) {
#pragma unroll
        for (int n = 0; n < 4; ++n) {
            int col   = wc * 64 + n * 16 + lrow;
            float sxj = snxB[col];
            float syj = snyB[col];
#pragma unroll
            for (int r = 0; r < 4; ++r) {
                int rowi  = wr * 64 + m * 16 + kgrp * 4 + r;
                float d2x = snxA[rowi] + sxj - 2.f * accX[m][n][r];
                float dxv = sqrtf(fmaxf(d2x, 1e-12f));
                float d2y = snyA[rowi] + syj - 2.f * accY[m][n][r];
                float dyv = sqrtf(fmaxf(d2y, 1e-12f));
                int gi = iA + rowi, gj = iB + col;
                bool keep = (gi != gj) && (dxv <= EPS_THR);
                float contrib = __expf(-dxv * SIGMA_INV) * dyv;
                local += keep ? contrib : 0.f;
            }
        }
    }
    if (!diag) local *= 2.f;

#pragma unroll
    for (int off = 32; off > 0; off >>= 1)
        local += __shfl_down(local, off, 64);
    if (lane == 0) wsum[wid] = local;
    __syncthreads();
    if (tid == 0)
        atomicAdd(out, wsum[0] + wsum[1] + wsum[2] + wsum[3]);
}

// ===========================================================================
// FALLBACK PATH (bf16, round-2 structure) — used only if ws too small.
// ===========================================================================
__global__ void norms_kernel_fb(const float* __restrict__ x,
                                const float* __restrict__ y,
                                float* __restrict__ sqx,
                                float* __restrict__ sqy) {
    int row = blockIdx.x;
    int t   = threadIdx.x;
    const float4* xr = (const float4*)(x + (size_t)row * D_X);
    float sx = 0.f;
#pragma unroll
    for (int i = 0; i < D_X / 4 / 64; ++i) {
        float4 v = xr[t + i * 64];
        sx += v.x * v.x + v.y * v.y + v.z * v.z + v.w * v.w;
    }
    const float4* yr = (const float4*)(y + (size_t)row * D_Y);
    float sy = 0.f;
#pragma unroll
    for (int i = 0; i < D_Y / 4 / 64; ++i) {
        float4 v = yr[t + i * 64];
        sy += v.x * v.x + v.y * v.y + v.z * v.z + v.w * v.w;
    }
#pragma unroll
    for (int off = 32; off > 0; off >>= 1) {
        sx += __shfl_down(sx, off, 64);
        sy += __shfl_down(sy, off, 64);
    }
    if (t == 0) { sqx[row] = sx; sqy[row] = sy; }
}

__device__ __forceinline__ void stage_tile_fb(const float* __restrict__ src, int ld,
                                              int base_row, int k0,
                                              u16x8* __restrict__ dst, int tid) {
#pragma unroll
    for (int it = 0; it < 2; ++it) {
        int u   = tid + it * 256;
        int row = u >> 2;
        int q   = u & 3;
        const float4* p = (const float4*)(src + (size_t)(base_row + row) * ld + k0 + q * 16);
        float4 f0 = p[0], f1 = p[1], f2 = p[2], f3 = p[3];
        u16x8 lo, hi;
        lo[0] = f32_to_bf16_bits(f0.x); lo[1] = f32_to_bf16_bits(f0.y);
        lo[2] = f32_to_bf16_bits(f0.z); lo[3] = f32_to_bf16_bits(f0.w);
        lo[4] = f32_to_bf16_bits(f1.x); lo[5] = f32_to_bf16_bits(f1.y);
        lo[6] = f32_to_bf16_bits(f1.z); lo[7] = f32_to_bf16_bits(f1.w);
        hi[0] = f32_to_bf16_bits(f2.x); hi[1] = f32_to_bf16_bits(f2.y);
        hi[2] = f32_to_bf16_bits(f2.z); hi[3] = f32_to_bf16_bits(f2.w);
        hi[4] = f32_to_bf16_bits(f3.x); hi[5] = f32_to_bf16_bits(f3.y);
        hi[6] = f32_to_bf16_bits(f3.z); hi[7] = f32_to_bf16_bits(f3.w);
        int swz = row & 7;
        dst[row * 8 + ((2 * q) ^ swz)]     = lo;
        dst[row * 8 + ((2 * q + 1) ^ swz)] = hi;
    }
}

__device__ __forceinline__ void mfma16_fb(const bf16x8 a[4], const bf16x8 b[4],
                                          f32x4 acc[4][4]) {
#pragma unroll
    for (int m = 0; m < 4; ++m)
#pragma unroll
        for (int n = 0; n < 4; ++n)
            acc[m][n] = __builtin_amdgcn_mfma_f32_16x16x32_bf16(
                a[m], b[n], acc[m][n], 0, 0, 0);
}

__device__ __forceinline__ void load_frags_fb(const u16x8* As_, const u16x8* Bs_,
                                              int wr, int wc, int lrow, int kgrp,
                                              bf16x8 a[2][4], bf16x8 b[2][4]) {
#pragma unroll
    for (int ks = 0; ks < 2; ++ks) {
#pragma unroll
        for (int m = 0; m < 4; ++m) {
            int row  = wr * 64 + m * 16 + lrow;
            int slot = (ks * 4 + kgrp) ^ (row & 7);
            a[ks][m] = __builtin_bit_cast(bf16x8, As_[row * 8 + slot]);
        }
#pragma unroll
        for (int n = 0; n < 4; ++n) {
            int row  = wc * 64 + n * 16 + lrow;
            int slot = (ks * 4 + kgrp) ^ (row & 7);
            b[ks][n] = __builtin_bit_cast(bf16x8, Bs_[row * 8 + slot]);
        }
    }
}

__global__ void __launch_bounds__(256, 2)
graph_loss_fb(const float* __restrict__ x, const float* __restrict__ y,
              const float* __restrict__ sqx, const float* __restrict__ sqy,
              float* __restrict__ out) {
    __shared__ u16x8 As[BM * 8];
    __shared__ u16x8 Bs[BM * 8];
    __shared__ float snxA[BM], snxB[BM], snyA[BM], snyB[BM];
    __shared__ float wsum[4];

    const int tid  = threadIdx.x;
    const int lane = tid & 63;
    const int wid  = tid >> 6;
    const int wr   = wid >> 1;
    const int wc   = wid & 1;
    const int lrow = lane & 15;
    const int kgrp = lane >> 4;

    int t = blockIdx.x, bi = 0;
    while (t >= NT - bi) { t -= NT - bi; ++bi; }
    const int bj = bi + t;
    const int iA = bi * BM;
    const int iB = bj * BM;

    if (tid < BM) {
        snxA[tid] = sqx[iA + tid];
        snyA[tid] = sqy[iA + tid];
        snxB[tid] = sqx[iB + tid];
        snyB[tid] = sqy[iB + tid];
    }

    f32x4 accX[4][4] = {};
    f32x4 accY[4][4] = {};
    bf16x8 a[2][4], b[2][4];

    for (int kt = 0; kt < D_X / 64; ++kt) {
        __syncthreads();
        stage_tile_fb(x, D_X, iA, kt * 64, As, tid);
        stage_tile_fb(x, D_X, iB, kt * 64, Bs, tid);
        __syncthreads();
        load_frags_fb(As, Bs, wr, wc, lrow, kgrp, a, b);
#pragma unroll
        for (int ks = 0; ks < 2; ++ks) mfma16_fb(a[ks], b[ks], accX);
    }
    for (int kt = 0; kt < D_Y / 64; ++kt) {
        __syncthreads();
        stage_tile_fb(y, D_Y, iA, kt * 64, As, tid);
        stage_tile_fb(y, D_Y, iB, kt * 64, Bs, tid);
        __syncthreads();
        load_frags_fb(As, Bs, wr, wc, lrow, kgrp, a, b);
#pragma unroll
        for (int ks = 0; ks < 2; ++ks) mfma16_fb(a[ks], b[ks], accY);
    }

    float local = 0.f;
#pragma unroll
    for (int m = 0; m < 4; ++m) {
#pragma unroll
        for (int n = 0; n < 4; ++n) {
            int col   = wc * 64 + n * 16 + lrow;
            float sxj = snxB[col];
            float syj = snyB[col];
#pragma unroll
            for (int r = 0; r < 4; ++r) {
                int rowi  = wr * 64 + m * 16 + kgrp * 4 + r;
                float d2x = snxA[rowi] + sxj - 2.f * accX[m][n][r];
                float dxv = sqrtf(fmaxf(d2x, 1e-12f));
                float d2y = snyA[rowi] + syj - 2.f * accY[m][n][r];
                float dyv = sqrtf(fmaxf(d2y, 1e-12f));
                int gi = iA + rowi, gj = iB + col;
                bool keep = (gi != gj) && (dxv <= EPS_THR);
                float contrib = __expf(-dxv * SIGMA_INV) * dyv;
                local += keep ? contrib : 0.f;
            }
        }
    }
    if (bi != bj) local *= 2.f;

#pragma unroll
    for (int off = 32; off > 0; off >>= 1)
        local += __shfl_down(local, off, 64);
    if (lane == 0) wsum[wid] = local;
    __syncthreads();
    if (tid == 0)
        atomicAdd(out, wsum[0] + wsum[1] + wsum[2] + wsum[3]);
}

// ===========================================================================
extern "C" void kernel_launch(void* const* d_in, const int* in_sizes, int n_in,
                              void* d_out, int out_size, void* d_ws, size_t ws_size,
                              hipStream_t stream) {
    const float* x = (const float*)d_in[0];
    const float* y = (const float*)d_in[1];
    float* out = (float*)d_out;

    hipMemsetAsync(d_out, 0, sizeof(float) * (size_t)out_size, stream);

    const size_t xq_bytes = (size_t)BATCH * D_X;        // 4 MB fp8
    const size_t yq_bytes = (size_t)BATCH * D_Y;        // 2 MB fp8
    const size_t sq_bytes = 2 * (size_t)BATCH * sizeof(float);
    const size_t need = xq_bytes + yq_bytes + sq_bytes;

    if (ws_size >= need) {
        u64*   xq  = (u64*)d_ws;
        u64*   yq  = (u64*)((char*)d_ws + xq_bytes);
        float* sqx = (float*)((char*)d_ws + xq_bytes + yq_bytes);
        float* sqy = sqx + BATCH;
        convert_fp8<<<BATCH, 192, 0, stream>>>(x, y, xq, yq, sqx, sqy);
        gram_fp8<<<NBLKF, 256, 0, stream>>>((const u16x8*)xq, (const u16x8*)yq,
                                            sqx, sqy, out);
    } else {
        float* sqx = (float*)d_ws;
        float* sqy = sqx + BATCH;
        norms_kernel_fb<<<BATCH, 64, 0, stream>>>(x, y, sqx, sqy);
        graph_loss_fb<<<NBLK, 256, 0, stream>>>(x, y, sqx, sqy, out);
    }
}